// Round 1
// baseline (62.291 us; speedup 1.0000x reference)
//
#include <hip/hip_runtime.h>

// Problem constants (match reference)
#define BB    32
#define N_OPC 512
#define N_MAC 64
#define FF    8
#define HH    128
#define OO    8
#define TM    16      // rows per block
#define HSTR  18      // padded LDS row stride (floats) for hT/gT

__device__ __forceinline__ float elu_f(float x) {
    return x > 0.0f ? x : (__expf(x) - 1.0f);
}

// Input layer: K -> 128, input xS is LDS [TM][K] row-major, w is (K,128), ELU on out.
// outT is transposed [col][row] with stride HSTR.
template<int K>
__device__ __forceinline__ void layer_in(const float* __restrict__ xS,
                                         const float* __restrict__ w,
                                         const float* __restrict__ bias,
                                         float (* __restrict__ outT)[HSTR], int tid)
{
    const int j  = tid & (HH - 1);   // output column 0..127
    const int rh = tid >> 7;         // row half 0..1
    float wreg[K];
    #pragma unroll
    for (int k = 0; k < K; ++k) wreg[k] = w[k * HH + j];
    const float bj = bias[j];
    #pragma unroll
    for (int i = 0; i < TM / 2; ++i) {
        const int r = rh * (TM / 2) + i;
        float acc = bj;
        #pragma unroll
        for (int k = 0; k < K; ++k) acc = fmaf(xS[r * K + k], wreg[k], acc);
        outT[j][r] = elu_f(acc);
    }
}

// Heavy layer: 128 -> 128 with ELU. inT/outT transposed [k][row], stride HSTR.
__device__ __forceinline__ void layer_hh(const float (* __restrict__ inT)[HSTR],
                                         const float* __restrict__ w,
                                         const float* __restrict__ bias,
                                         float (* __restrict__ outT)[HSTR], int tid)
{
    const int rt = tid & 7;          // 8 row-tiles of 2 rows
    const int jt = tid >> 3;         // 32 col-tiles of 4 cols
    const int r0 = rt * 2, j0 = jt * 4;
    const float4 bj = *(const float4*)(bias + j0);
    float acc[2][4] = {{bj.x, bj.y, bj.z, bj.w}, {bj.x, bj.y, bj.z, bj.w}};
    #pragma unroll 4
    for (int k = 0; k < HH; ++k) {
        const float2 hv = *(const float2*)&inT[k][r0];
        const float4 wv = *(const float4*)(w + k * HH + j0);
        acc[0][0] = fmaf(hv.x, wv.x, acc[0][0]);
        acc[0][1] = fmaf(hv.x, wv.y, acc[0][1]);
        acc[0][2] = fmaf(hv.x, wv.z, acc[0][2]);
        acc[0][3] = fmaf(hv.x, wv.w, acc[0][3]);
        acc[1][0] = fmaf(hv.y, wv.x, acc[1][0]);
        acc[1][1] = fmaf(hv.y, wv.y, acc[1][1]);
        acc[1][2] = fmaf(hv.y, wv.z, acc[1][2]);
        acc[1][3] = fmaf(hv.y, wv.w, acc[1][3]);
    }
    #pragma unroll
    for (int c = 0; c < 4; ++c) {
        outT[j0 + c][r0 + 0] = elu_f(acc[0][c]);
        outT[j0 + c][r0 + 1] = elu_f(acc[1][c]);
    }
}

// Output layer partials: 128 -> 8, split-K across the two half-blocks.
__device__ __forceinline__ void layer_ho(const float (* __restrict__ inT)[HSTR],
                                         const float* __restrict__ w,
                                         float (* __restrict__ part)[TM][OO], int tid)
{
    const int item = tid & 127;
    const int half = tid >> 7;
    const int r = item >> 3, o = item & 7;
    const int k0 = half * (HH / 2);
    float acc = 0.0f;
    #pragma unroll 8
    for (int kk = 0; kk < HH / 2; ++kk) {
        const int k = k0 + kk;
        acc = fmaf(inT[k][r], w[k * OO + o], acc);
    }
    part[half][r][o] = acc;
}

__global__ __launch_bounds__(256, 4) void mlps_kernel(
    const int*   __restrict__ adj,   // (B, N_OP, N_MA) int32
    const float* __restrict__ fop,   // (B, N_OP, F)
    const float* __restrict__ fmab,  // (B, N_MA, F)
    const float* __restrict__ l0w1, const float* __restrict__ l0b1,
    const float* __restrict__ l0w2, const float* __restrict__ l0b2,
    const float* __restrict__ l0w3, const float* __restrict__ l0b3,
    const float* __restrict__ l1w1, const float* __restrict__ l1b1,
    const float* __restrict__ l1w2, const float* __restrict__ l1b2,
    const float* __restrict__ l1w3, const float* __restrict__ l1b3,
    const float* __restrict__ pw1,  const float* __restrict__ pb1,
    const float* __restrict__ pw2,  const float* __restrict__ pb2,
    const float* __restrict__ pw3,  const float* __restrict__ pb3,
    float* __restrict__ out)
{
    __shared__ float xinS[TM][FF];        // aggregated machine feats
    __shared__ float xopS[TM][FF];        // op feats
    __shared__ float catS[TM][2 * OO];    // elu(concat(emb0, emb1))
    __shared__ float hT[HH][HSTR];        // ping
    __shared__ float gT[HH][HSTR];        // pong
    __shared__ float part[2][TM][OO];     // split-K partials
    __shared__ float fmS[N_MAC][FF];      // machine feats for this batch
    __shared__ int   adjS[TM][N_MAC];     // adjacency rows

    const int tid  = threadIdx.x;
    const int blk  = blockIdx.x;
    const int row0 = blk * TM;            // global row base (b*N_OP + n)
    const int b    = row0 / N_OPC;        // TM divides N_OP -> single batch per block

    // ---- stage: adj rows, machine feats, op feats
    {
        const int* asrc = adj + row0 * N_MAC;
        #pragma unroll
        for (int i = 0; i < (TM * N_MAC) / 256; ++i)
            ((int*)adjS)[tid + i * 256] = asrc[tid + i * 256];
        const float* msrc = fmab + b * N_MAC * FF;
        #pragma unroll
        for (int i = 0; i < (N_MAC * FF) / 256; ++i)
            ((float*)fmS)[tid + i * 256] = msrc[tid + i * 256];
        if (tid < TM * FF)
            ((float*)xopS)[tid] = fop[row0 * FF + tid];
    }
    __syncthreads();

    // ---- aggregation: xin[r][f] = sum_m adj[r][m] * fm[m][f]
    if (tid < TM * FF) {
        const int r = tid / FF, f = tid % FF;
        float acc = 0.0f;
        #pragma unroll 8
        for (int m = 0; m < N_MAC; ++m)
            acc = fmaf((float)adjS[r][m], fmS[m][f], acc);
        xinS[r][f] = acc;
    }
    __syncthreads();

    // ---- MLP 0 (machine aggregation branch)
    layer_in<FF>(&xinS[0][0], l0w1, l0b1, hT, tid);
    __syncthreads();
    layer_hh(hT, l0w2, l0b2, gT, tid);
    __syncthreads();
    layer_ho(gT, l0w3, part, tid);
    __syncthreads();
    if (tid < TM * OO) {
        const int r = tid >> 3, o = tid & 7;
        catS[r][o] = elu_f(part[0][r][o] + part[1][r][o] + l0b3[o]);
    }
    // ---- MLP 1 (self-loop branch) — layer_in can overlap with catS writes
    layer_in<FF>(&xopS[0][0], l1w1, l1b1, hT, tid);
    __syncthreads();
    layer_hh(hT, l1w2, l1b2, gT, tid);
    __syncthreads();
    layer_ho(gT, l1w3, part, tid);
    __syncthreads();
    if (tid < TM * OO) {
        const int r = tid >> 3, o = tid & 7;
        catS[r][OO + o] = elu_f(part[0][r][o] + part[1][r][o] + l1b3[o]);
    }
    __syncthreads();

    // ---- Final projection: elu(cat) -> 128 -> 128 -> 8
    layer_in<2 * OO>(&catS[0][0], pw1, pb1, hT, tid);
    __syncthreads();
    layer_hh(hT, pw2, pb2, gT, tid);
    __syncthreads();
    layer_ho(gT, pw3, part, tid);
    __syncthreads();
    if (tid < TM * OO) {
        const int r = tid >> 3, o = tid & 7;
        out[row0 * OO + tid] = part[0][r][o] + part[1][r][o] + pb3[o];
    }
}

extern "C" void kernel_launch(void* const* d_in, const int* in_sizes, int n_in,
                              void* d_out, int out_size, void* d_ws, size_t ws_size,
                              hipStream_t stream) {
    (void)in_sizes; (void)n_in; (void)out_size; (void)d_ws; (void)ws_size;
    const int*   adj  = (const int*)  d_in[0];
    const float* fop  = (const float*)d_in[1];
    const float* fmab = (const float*)d_in[2];
    const float* l0w1 = (const float*)d_in[3];
    const float* l0b1 = (const float*)d_in[4];
    const float* l0w2 = (const float*)d_in[5];
    const float* l0b2 = (const float*)d_in[6];
    const float* l0w3 = (const float*)d_in[7];
    const float* l0b3 = (const float*)d_in[8];
    const float* l1w1 = (const float*)d_in[9];
    const float* l1b1 = (const float*)d_in[10];
    const float* l1w2 = (const float*)d_in[11];
    const float* l1b2 = (const float*)d_in[12];
    const float* l1w3 = (const float*)d_in[13];
    const float* l1b3 = (const float*)d_in[14];
    const float* pw1  = (const float*)d_in[15];
    const float* pb1  = (const float*)d_in[16];
    const float* pw2  = (const float*)d_in[17];
    const float* pb2  = (const float*)d_in[18];
    const float* pw3  = (const float*)d_in[19];
    const float* pb3  = (const float*)d_in[20];
    float* out = (float*)d_out;

    const int nrows = BB * N_OPC;            // 16384
    const int grid  = nrows / TM;            // 1024 blocks
    mlps_kernel<<<dim3(grid), dim3(256), 0, stream>>>(
        adj, fop, fmab,
        l0w1, l0b1, l0w2, l0b2, l0w3, l0b3,
        l1w1, l1b1, l1w2, l1b2, l1w3, l1b3,
        pw1, pb1, pw2, pb2, pw3, pb3,
        out);
}